// Round 1
// baseline (1777.712 us; speedup 1.0000x reference)
//
#include <hip/hip_runtime.h>
#include <hip/hip_bf16.h>

#define N_NODES 50000
#define N_EDGES 800000
#define IN_DIM  128
#define OUT_DIM 256

// ---------------- degree computation ----------------
__global__ __launch_bounds__(256) void deg_kernel(
    const int* __restrict__ src, const int* __restrict__ dst,
    float* __restrict__ deg_out, float* __restrict__ deg_in, int E)
{
    int e = blockIdx.x * blockDim.x + threadIdx.x;
    if (e < E) {
        atomicAdd(&deg_out[src[e]], 1.0f);
        atomicAdd(&deg_in[dst[e]], 1.0f);
    }
}

// ---------------- gather * rsqrt(deg_out) -> scatter-add ----------------
// 32 threads per edge, each thread handles 4 contiguous floats (128 dims).
__global__ __launch_bounds__(256) void scatter_kernel(
    const float* __restrict__ feats, const int* __restrict__ src,
    const int* __restrict__ dst, const float* __restrict__ deg_out,
    float* __restrict__ agg, int E)
{
    int gid  = blockIdx.x * blockDim.x + threadIdx.x;
    int e    = gid >> 5;
    int lane = gid & 31;
    if (e >= E) return;
    int s = src[e];
    int d = dst[e];
    float sc = rsqrtf(fmaxf(deg_out[s], 1.0f));
    const float4 v = *reinterpret_cast<const float4*>(&feats[s * IN_DIM + lane * 4]);
    float* base = &agg[d * IN_DIM + lane * 4];
    atomicAdd(base + 0, v.x * sc);
    atomicAdd(base + 1, v.y * sc);
    atomicAdd(base + 2, v.z * sc);
    atomicAdd(base + 3, v.w * sc);
}

// ---------------- fused (optional deg scale) GEMM + bias + SiLU ----------------
// Block: 256 threads. Each block computes 16 rows x 256 cols.
// Thread t owns output column t for all 16 rows.
// A tile (16 x K) staged in LDS; W streamed (L2-resident after first block).
// Safe for in-place A==out: tile is loaded to LDS before any writes, and a
// block only writes its own 16 rows.
template <int K>
__global__ __launch_bounds__(256) void gemm_silu_kernel(
    const float* __restrict__ A, const float* __restrict__ W,
    const float* __restrict__ bias, float* __restrict__ out,
    const float* __restrict__ deg_in, int M)
{
    __shared__ float As[16][K];   // K=128: 8KB, K=256: 16KB
    const int row0 = blockIdx.x * 16;
    const int tid  = threadIdx.x;

    // stage A tile (optionally scaled by rsqrt(clip(deg_in,1)))
    for (int idx = tid; idx < 16 * K; idx += 256) {
        int r = idx / K, c = idx % K;
        int row = row0 + r;
        float v = 0.0f;
        if (row < M) {
            v = A[row * K + c];
            if (deg_in) v *= rsqrtf(fmaxf(deg_in[row], 1.0f));
        }
        As[r][c] = v;
    }
    __syncthreads();

    float acc[16];
    const float b = bias[tid];
    #pragma unroll
    for (int r = 0; r < 16; ++r) acc[r] = b;

    for (int k = 0; k < K; ++k) {
        float wv = W[k * OUT_DIM + tid];
        #pragma unroll
        for (int r = 0; r < 16; ++r) acc[r] = fmaf(As[r][k], wv, acc[r]);
    }

    #pragma unroll
    for (int r = 0; r < 16; ++r) {
        int row = row0 + r;
        if (row < M) {
            float x = acc[r];
            out[row * OUT_DIM + tid] = x / (1.0f + expf(-x));   // SiLU
        }
    }
}

extern "C" void kernel_launch(void* const* d_in, const int* in_sizes, int n_in,
                              void* d_out, int out_size, void* d_ws, size_t ws_size,
                              hipStream_t stream)
{
    const float* feats  = (const float*)d_in[0];
    const float* W_conv = (const float*)d_in[1];
    const float* b_conv = (const float*)d_in[2];
    const float* W1     = (const float*)d_in[3];
    const float* b1     = (const float*)d_in[4];
    const float* W2     = (const float*)d_in[5];
    const float* b2     = (const float*)d_in[6];
    const int*   src    = (const int*)d_in[7];
    const int*   dst    = (const int*)d_in[8];
    float* out = (float*)d_out;

    // workspace layout (bytes):
    //   [0, 200000)               deg_out  (50000 f32)
    //   [200000, 400000)          deg_in   (50000 f32)
    //   [400000, 26000000)        agg      (50000 x 128 f32)
    //   [26000000, 77200000)      h1       (50000 x 256 f32)
    char* ws = (char*)d_ws;
    float* deg_out = (float*)(ws + 0);
    float* deg_in  = (float*)(ws + 200000);
    float* agg     = (float*)(ws + 400000);
    float* h1      = (float*)(ws + 26000000);

    // zero the atomically-accumulated regions (deg_out, deg_in, agg)
    hipMemsetAsync(d_ws, 0, 26000000, stream);

    // degrees
    deg_kernel<<<(N_EDGES + 255) / 256, 256, 0, stream>>>(src, dst, deg_out, deg_in, N_EDGES);

    // gather/scale/scatter: 32 threads per edge
    {
        long long total = (long long)N_EDGES * 32;
        int blocks = (int)((total + 255) / 256);
        scatter_kernel<<<blocks, 256, 0, stream>>>(feats, src, dst, deg_out, agg, N_EDGES);
    }

    const int gemm_blocks = (N_NODES + 15) / 16;
    // layer 1: h1 = silu((agg * rsqrt(deg_in)) @ W_conv + b_conv), K=128
    gemm_silu_kernel<IN_DIM><<<gemm_blocks, 256, 0, stream>>>(agg, W_conv, b_conv, h1, deg_in, N_NODES);
    // layer 2: h2 = silu(h1 @ W1 + b1) -> d_out, K=256
    gemm_silu_kernel<OUT_DIM><<<gemm_blocks, 256, 0, stream>>>(h1, W1, b1, out, nullptr, N_NODES);
    // layer 3: out = silu(h2 @ W2 + b2), in-place on d_out, K=256
    gemm_silu_kernel<OUT_DIM><<<gemm_blocks, 256, 0, stream>>>(out, W2, b2, out, nullptr, N_NODES);
}

// Round 2
// 533.804 us; speedup vs baseline: 3.3303x; 3.3303x over previous
//
#include <hip/hip_runtime.h>
#include <hip/hip_bf16.h>

#define N_NODES 50000
#define N_EDGES 800000
#define IN_DIM  128
#define OUT_DIM 256

// ---------------- int degree histograms ----------------
__global__ __launch_bounds__(256) void hist_kernel(
    const int* __restrict__ src, const int* __restrict__ dst,
    int* __restrict__ cnt_src, int* __restrict__ cnt_dst, int E)
{
    int e = blockIdx.x * blockDim.x + threadIdx.x;
    if (e < E) {
        atomicAdd(&cnt_src[src[e]], 1);
        atomicAdd(&cnt_dst[dst[e]], 1);
    }
}

// ---------------- exclusive scan of cnt_dst -> offs[N_NODES+1] ----------------
__global__ __launch_bounds__(1024) void scan_kernel(
    const int* __restrict__ cnt, int* __restrict__ offs)
{
    __shared__ int part[1024];
    const int CHUNK = (N_NODES + 1023) / 1024;   // 49
    int tid = threadIdx.x;
    int begin = tid * CHUNK;
    int end = min(begin + CHUNK, N_NODES);
    int s = 0;
    for (int i = begin; i < end; ++i) s += cnt[i];
    part[tid] = s;
    __syncthreads();
    for (int off = 1; off < 1024; off <<= 1) {
        int v = (tid >= off) ? part[tid - off] : 0;
        __syncthreads();
        part[tid] += v;
        __syncthreads();
    }
    int run = (tid == 0) ? 0 : part[tid - 1];
    for (int i = begin; i < end; ++i) { offs[i] = run; run += cnt[i]; }
    if (tid == 1023) offs[N_NODES] = part[1023];   // total = N_EDGES
}

// ---------------- permute edges into CSR-by-dst (consumes cnt_dst) ----------------
__global__ __launch_bounds__(256) void build_csr_kernel(
    const int* __restrict__ src, const int* __restrict__ dst,
    const int* __restrict__ offs, int* __restrict__ cnt_dst,
    int* __restrict__ edge_src, int E)
{
    int e = blockIdx.x * blockDim.x + threadIdx.x;
    if (e < E) {
        int d = dst[e];
        int slot = atomicSub(&cnt_dst[d], 1) - 1;  // deg-1 .. 0, unique
        edge_src[offs[d] + slot] = src[e];
    }
}

// ---------------- gather-aggregate: 32 lanes per node, no atomics ----------------
__global__ __launch_bounds__(256) void aggregate_kernel(
    const float* __restrict__ feats, const int* __restrict__ edge_src,
    const int* __restrict__ offs, const int* __restrict__ cnt_src,
    float* __restrict__ agg, int M)
{
    int gid  = blockIdx.x * 256 + threadIdx.x;
    int n    = gid >> 5;
    int lane = gid & 31;
    if (n >= M) return;
    int beg = offs[n], end = offs[n + 1];
    float4 acc0 = make_float4(0, 0, 0, 0);
    float4 acc1 = make_float4(0, 0, 0, 0);
    int j = beg;
    for (; j + 1 < end; j += 2) {
        int s0 = edge_src[j], s1 = edge_src[j + 1];
        float sc0 = rsqrtf(fmaxf((float)cnt_src[s0], 1.0f));
        float sc1 = rsqrtf(fmaxf((float)cnt_src[s1], 1.0f));
        float4 v0 = *reinterpret_cast<const float4*>(&feats[(size_t)s0 * IN_DIM + lane * 4]);
        float4 v1 = *reinterpret_cast<const float4*>(&feats[(size_t)s1 * IN_DIM + lane * 4]);
        acc0.x = fmaf(v0.x, sc0, acc0.x); acc0.y = fmaf(v0.y, sc0, acc0.y);
        acc0.z = fmaf(v0.z, sc0, acc0.z); acc0.w = fmaf(v0.w, sc0, acc0.w);
        acc1.x = fmaf(v1.x, sc1, acc1.x); acc1.y = fmaf(v1.y, sc1, acc1.y);
        acc1.z = fmaf(v1.z, sc1, acc1.z); acc1.w = fmaf(v1.w, sc1, acc1.w);
    }
    if (j < end) {
        int s0 = edge_src[j];
        float sc0 = rsqrtf(fmaxf((float)cnt_src[s0], 1.0f));
        float4 v0 = *reinterpret_cast<const float4*>(&feats[(size_t)s0 * IN_DIM + lane * 4]);
        acc0.x = fmaf(v0.x, sc0, acc0.x); acc0.y = fmaf(v0.y, sc0, acc0.y);
        acc0.z = fmaf(v0.z, sc0, acc0.z); acc0.w = fmaf(v0.w, sc0, acc0.w);
    }
    float di = rsqrtf(fmaxf((float)(end - beg), 1.0f));
    float4 o;
    o.x = (acc0.x + acc1.x) * di;
    o.y = (acc0.y + acc1.y) * di;
    o.z = (acc0.z + acc1.z) * di;
    o.w = (acc0.w + acc1.w) * di;
    *reinterpret_cast<float4*>(&agg[(size_t)n * IN_DIM + lane * 4]) = o;
}

// ---------------- 64x64 register-tiled GEMM + bias + SiLU ----------------
// Block = 256 threads, each computes a 4x4 output tile. Grid (N/64, M/64).
template <int K>
__global__ __launch_bounds__(256) void gemm64_kernel(
    const float* __restrict__ A, const float* __restrict__ W,
    const float* __restrict__ bias, float* __restrict__ out, int M)
{
    __shared__ float As[64][68];   // padded: conflict-free b128 reads
    __shared__ float Ws[64][64];
    const int tid  = threadIdx.x;
    const int cgrp = tid & 15;     // 0..15
    const int rgrp = tid >> 4;     // 0..15
    const int c0 = cgrp * 4;
    const int r0 = rgrp * 4;
    const int col_base = blockIdx.x * 64;
    const int row_base = blockIdx.y * 64;

    float acc[4][4];
    #pragma unroll
    for (int i = 0; i < 4; ++i)
        #pragma unroll
        for (int j = 0; j < 4; ++j) acc[i][j] = 0.0f;

    for (int kt = 0; kt < K; kt += 64) {
        // stage A tile: rows 0..63 of [row_base..], k = kt..kt+63
        #pragma unroll
        for (int rr = 0; rr < 4; ++rr) {
            int r  = rgrp + rr * 16;
            int gr = row_base + r;
            float4 v = make_float4(0, 0, 0, 0);
            if (gr < M) v = *reinterpret_cast<const float4*>(&A[(size_t)gr * K + kt + c0]);
            *reinterpret_cast<float4*>(&As[r][c0]) = v;
        }
        // stage W tile: k = kt..kt+63, cols col_base..col_base+63
        #pragma unroll
        for (int kk_ = 0; kk_ < 4; ++kk_) {
            int k = rgrp + kk_ * 16;
            float4 v = *reinterpret_cast<const float4*>(&W[(size_t)(kt + k) * OUT_DIM + col_base + c0]);
            *reinterpret_cast<float4*>(&Ws[k][c0]) = v;
        }
        __syncthreads();

        #pragma unroll
        for (int kk = 0; kk < 64; kk += 4) {
            float4 a[4], w[4];
            #pragma unroll
            for (int i = 0; i < 4; ++i) a[i] = *reinterpret_cast<const float4*>(&As[r0 + i][kk]);
            #pragma unroll
            for (int j4 = 0; j4 < 4; ++j4) w[j4] = *reinterpret_cast<const float4*>(&Ws[kk + j4][c0]);
            #pragma unroll
            for (int kj = 0; kj < 4; ++kj) {
                #pragma unroll
                for (int i = 0; i < 4; ++i) {
                    float av = (kj == 0) ? a[i].x : (kj == 1) ? a[i].y : (kj == 2) ? a[i].z : a[i].w;
                    acc[i][0] = fmaf(av, w[kj].x, acc[i][0]);
                    acc[i][1] = fmaf(av, w[kj].y, acc[i][1]);
                    acc[i][2] = fmaf(av, w[kj].z, acc[i][2]);
                    acc[i][3] = fmaf(av, w[kj].w, acc[i][3]);
                }
            }
        }
        __syncthreads();
    }

    float4 b = *reinterpret_cast<const float4*>(&bias[col_base + c0]);
    #pragma unroll
    for (int i = 0; i < 4; ++i) {
        int gr = row_base + r0 + i;
        if (gr < M) {
            float x0 = acc[i][0] + b.x, x1 = acc[i][1] + b.y;
            float x2 = acc[i][2] + b.z, x3 = acc[i][3] + b.w;
            float4 o;
            o.x = x0 / (1.0f + expf(-x0));
            o.y = x1 / (1.0f + expf(-x1));
            o.z = x2 / (1.0f + expf(-x2));
            o.w = x3 / (1.0f + expf(-x3));
            *reinterpret_cast<float4*>(&out[(size_t)gr * OUT_DIM + col_base + c0]) = o;
        }
    }
}

extern "C" void kernel_launch(void* const* d_in, const int* in_sizes, int n_in,
                              void* d_out, int out_size, void* d_ws, size_t ws_size,
                              hipStream_t stream)
{
    const float* feats  = (const float*)d_in[0];
    const float* W_conv = (const float*)d_in[1];
    const float* b_conv = (const float*)d_in[2];
    const float* W1     = (const float*)d_in[3];
    const float* b1     = (const float*)d_in[4];
    const float* W2     = (const float*)d_in[5];
    const float* b2     = (const float*)d_in[6];
    const int*   src    = (const int*)d_in[7];
    const int*   dst    = (const int*)d_in[8];
    float* out = (float*)d_out;

    // workspace layout (bytes), total 55,000,016:
    //   [0, 51,200,000)            h1 (50000x256 f32)  -- also aliases agg (dead by layer 2)
    //   [51,200,000, 51,400,000)   cnt_src (int)
    //   [51,400,000, 51,600,000)   cnt_dst (int)
    //   [51,600,000, 51,800,004)   offs (int[N+1])
    //   [51,800,016, 55,000,016)   edge_src (int[E])
    char* ws = (char*)d_ws;
    float* h1       = (float*)(ws + 0);
    float* agg      = (float*)(ws + 0);          // alias: agg dead before h1 written
    int*   cnt_src  = (int*)(ws + 51200000);
    int*   cnt_dst  = (int*)(ws + 51400000);
    int*   offs     = (int*)(ws + 51600000);
    int*   edge_src = (int*)(ws + 51800016);

    // zero the two histogram arrays only
    hipMemsetAsync(ws + 51200000, 0, 400000, stream);

    hist_kernel<<<(N_EDGES + 255) / 256, 256, 0, stream>>>(src, dst, cnt_src, cnt_dst, N_EDGES);
    scan_kernel<<<1, 1024, 0, stream>>>(cnt_dst, offs);
    build_csr_kernel<<<(N_EDGES + 255) / 256, 256, 0, stream>>>(src, dst, offs, cnt_dst, edge_src, N_EDGES);

    {   // 32 lanes per node
        long long total = (long long)N_NODES * 32;
        int blocks = (int)((total + 255) / 256);
        aggregate_kernel<<<blocks, 256, 0, stream>>>(feats, edge_src, offs, cnt_src, agg, N_NODES);
    }

    dim3 ggrid(OUT_DIM / 64, (N_NODES + 63) / 64);   // (4, 782)
    // layer 1: d_out = silu(agg @ W_conv + b_conv)      (K=128)
    gemm64_kernel<IN_DIM><<<ggrid, 256, 0, stream>>>(agg, W_conv, b_conv, out, N_NODES);
    // layer 2: h1 = silu(d_out @ W1 + b1)               (K=256) -- agg now dead
    gemm64_kernel<OUT_DIM><<<ggrid, 256, 0, stream>>>(out, W1, b1, h1, N_NODES);
    // layer 3: d_out = silu(h1 @ W2 + b2)               (K=256)
    gemm64_kernel<OUT_DIM><<<ggrid, 256, 0, stream>>>(h1, W2, b2, out, N_NODES);
}

// Round 3
// 444.688 us; speedup vs baseline: 3.9977x; 1.2004x over previous
//
#include <hip/hip_runtime.h>
#include <hip/hip_bf16.h>

#define N_NODES 50000
#define N_EDGES 800000
#define IN_DIM  128
#define OUT_DIM 256

typedef short frag8 __attribute__((ext_vector_type(8)));   // 8 bf16 (4 VGPRs)
typedef float f32x4 __attribute__((ext_vector_type(4)));

// ---------------- int degree histograms ----------------
__global__ __launch_bounds__(256) void hist_kernel(
    const int* __restrict__ src, const int* __restrict__ dst,
    int* __restrict__ cnt_src, int* __restrict__ cnt_dst, int E)
{
    int e = blockIdx.x * blockDim.x + threadIdx.x;
    if (e < E) {
        atomicAdd(&cnt_src[src[e]], 1);
        atomicAdd(&cnt_dst[dst[e]], 1);
    }
}

// ---------------- exclusive scan of cnt_dst -> offs[N_NODES+1] ----------------
__global__ __launch_bounds__(1024) void scan_kernel(
    const int* __restrict__ cnt, int* __restrict__ offs)
{
    __shared__ int part[1024];
    const int CHUNK = (N_NODES + 1023) / 1024;   // 49
    int tid = threadIdx.x;
    int begin = tid * CHUNK;
    int end = min(begin + CHUNK, N_NODES);
    int s = 0;
    for (int i = begin; i < end; ++i) s += cnt[i];
    part[tid] = s;
    __syncthreads();
    for (int off = 1; off < 1024; off <<= 1) {
        int v = (tid >= off) ? part[tid - off] : 0;
        __syncthreads();
        part[tid] += v;
        __syncthreads();
    }
    int run = (tid == 0) ? 0 : part[tid - 1];
    for (int i = begin; i < end; ++i) { offs[i] = run; run += cnt[i]; }
    if (tid == 1023) offs[N_NODES] = part[1023];
}

// ---------------- permute edges into CSR-by-dst (consumes cnt_dst) ----------------
__global__ __launch_bounds__(256) void build_csr_kernel(
    const int* __restrict__ src, const int* __restrict__ dst,
    const int* __restrict__ offs, int* __restrict__ cnt_dst,
    int* __restrict__ edge_src, int E)
{
    int e = blockIdx.x * blockDim.x + threadIdx.x;
    if (e < E) {
        int d = dst[e];
        int slot = atomicSub(&cnt_dst[d], 1) - 1;
        edge_src[offs[d] + slot] = src[e];
    }
}

// ---------------- gather-aggregate: 32 lanes per node, no atomics ----------------
__global__ __launch_bounds__(256) void aggregate_kernel(
    const float* __restrict__ feats, const int* __restrict__ edge_src,
    const int* __restrict__ offs, const int* __restrict__ cnt_src,
    float* __restrict__ agg, int M)
{
    int gid  = blockIdx.x * 256 + threadIdx.x;
    int n    = gid >> 5;
    int lane = gid & 31;
    if (n >= M) return;
    int beg = offs[n], end = offs[n + 1];
    float4 acc0 = make_float4(0, 0, 0, 0);
    float4 acc1 = make_float4(0, 0, 0, 0);
    int j = beg;
    for (; j + 1 < end; j += 2) {
        int s0 = edge_src[j], s1 = edge_src[j + 1];
        float sc0 = rsqrtf(fmaxf((float)cnt_src[s0], 1.0f));
        float sc1 = rsqrtf(fmaxf((float)cnt_src[s1], 1.0f));
        float4 v0 = *reinterpret_cast<const float4*>(&feats[(size_t)s0 * IN_DIM + lane * 4]);
        float4 v1 = *reinterpret_cast<const float4*>(&feats[(size_t)s1 * IN_DIM + lane * 4]);
        acc0.x = fmaf(v0.x, sc0, acc0.x); acc0.y = fmaf(v0.y, sc0, acc0.y);
        acc0.z = fmaf(v0.z, sc0, acc0.z); acc0.w = fmaf(v0.w, sc0, acc0.w);
        acc1.x = fmaf(v1.x, sc1, acc1.x); acc1.y = fmaf(v1.y, sc1, acc1.y);
        acc1.z = fmaf(v1.z, sc1, acc1.z); acc1.w = fmaf(v1.w, sc1, acc1.w);
    }
    if (j < end) {
        int s0 = edge_src[j];
        float sc0 = rsqrtf(fmaxf((float)cnt_src[s0], 1.0f));
        float4 v0 = *reinterpret_cast<const float4*>(&feats[(size_t)s0 * IN_DIM + lane * 4]);
        acc0.x = fmaf(v0.x, sc0, acc0.x); acc0.y = fmaf(v0.y, sc0, acc0.y);
        acc0.z = fmaf(v0.z, sc0, acc0.z); acc0.w = fmaf(v0.w, sc0, acc0.w);
    }
    float di = rsqrtf(fmaxf((float)(end - beg), 1.0f));
    float4 o;
    o.x = (acc0.x + acc1.x) * di;
    o.y = (acc0.y + acc1.y) * di;
    o.z = (acc0.z + acc1.z) * di;
    o.w = (acc0.w + acc1.w) * di;
    *reinterpret_cast<float4*>(&agg[(size_t)n * IN_DIM + lane * 4]) = o;
}

// ---------------- W pre-split: W[k][n] f32 -> Wt_hi/Wt_lo [n][K] bf16 ----------------
__global__ __launch_bounds__(256) void wsplit_kernel(
    const float* __restrict__ W, ushort* __restrict__ Wt_hi,
    ushort* __restrict__ Wt_lo, int K)
{
    int idx = blockIdx.x * 256 + threadIdx.x;
    if (idx >= K * 256) return;
    int n = idx & 255, k = idx >> 8;
    float x = W[(size_t)k * 256 + n];
    unsigned u = __float_as_uint(x);
    ushort hi = (ushort)(u >> 16);
    float fhi = __uint_as_float(u & 0xFFFF0000u);
    float r = x - fhi;
    ushort lo = (ushort)(__float_as_uint(r) >> 16);
    Wt_hi[(size_t)n * K + k] = hi;
    Wt_lo[(size_t)n * K + k] = lo;
}

__device__ __forceinline__ void split2(float x, ushort& hi, ushort& lo) {
    unsigned u = __float_as_uint(x);
    hi = (ushort)(u >> 16);
    float fhi = __uint_as_float(u & 0xFFFF0000u);
    float r = x - fhi;
    lo = (ushort)(__float_as_uint(r) >> 16);
}

// ---------------- bf16x2-split MFMA GEMM + bias + SiLU ----------------
// 128x128 block tile, BK=32, 256 threads = 4 waves, each wave a 64x64 quadrant
// (4x4 fragments of v_mfma_f32_16x16x32_bf16; 3 MFMA per fragment: hh, hl, lh).
// LDS rows padded to 40 ushorts (80 B): 16B-aligned b128 reads, 2-way banks (free).
template <int K>
__global__ __launch_bounds__(256, 2) void gemm_mfma_kernel(
    const float* __restrict__ A, const ushort* __restrict__ Wt_hi,
    const ushort* __restrict__ Wt_lo, const float* __restrict__ bias,
    float* __restrict__ out, int M)
{
    __shared__ __align__(16) ushort As_hi[128][40];
    __shared__ __align__(16) ushort As_lo[128][40];
    __shared__ __align__(16) ushort Bs_hi[128][40];
    __shared__ __align__(16) ushort Bs_lo[128][40];

    const int tid  = threadIdx.x;
    const int lane = tid & 63;
    const int wave = tid >> 6;
    const int wr = wave >> 1, wc = wave & 1;
    const int row_base = blockIdx.y * 128;
    const int col_base = blockIdx.x * 128;
    const int fr = lane & 15;            // fragment row (A) / col (B,C)
    const int k0 = (lane >> 4) * 8;      // k segment

    f32x4 acc[4][4] = {};

    for (int kt = 0; kt < K; kt += 32) {
        if (kt) __syncthreads();
        // stage A tile (128 rows x 32 k), split f32 -> bf16 hi/lo
        #pragma unroll
        for (int i = 0; i < 4; ++i) {
            int f = i * 256 + tid;
            int r = f >> 3, c4 = f & 7;
            int gr = row_base + r;
            float4 v = make_float4(0.f, 0.f, 0.f, 0.f);
            if (gr < M) v = *reinterpret_cast<const float4*>(&A[(size_t)gr * K + kt + c4 * 4]);
            ushort4 h4, l4;
            split2(v.x, h4.x, l4.x); split2(v.y, h4.y, l4.y);
            split2(v.z, h4.z, l4.z); split2(v.w, h4.w, l4.w);
            *reinterpret_cast<ushort4*>(&As_hi[r][c4 * 4]) = h4;
            *reinterpret_cast<ushort4*>(&As_lo[r][c4 * 4]) = l4;
        }
        // stage B tile (128 cols x 32 k) from pre-split transposed weights
        #pragma unroll
        for (int i = 0; i < 4; ++i) {
            int c = i * 256 + tid;
            int n = c >> 3, k4 = c & 7;
            size_t go = (size_t)(col_base + n) * K + kt + k4 * 4;
            *reinterpret_cast<ushort4*>(&Bs_hi[n][k4 * 4]) =
                *reinterpret_cast<const ushort4*>(&Wt_hi[go]);
            *reinterpret_cast<ushort4*>(&Bs_lo[n][k4 * 4]) =
                *reinterpret_cast<const ushort4*>(&Wt_lo[go]);
        }
        __syncthreads();

        frag8 ah[4], al[4], bh[4], bl[4];
        #pragma unroll
        for (int m = 0; m < 4; ++m) {
            ah[m] = *reinterpret_cast<const frag8*>(&As_hi[wr * 64 + m * 16 + fr][k0]);
            al[m] = *reinterpret_cast<const frag8*>(&As_lo[wr * 64 + m * 16 + fr][k0]);
        }
        #pragma unroll
        for (int n = 0; n < 4; ++n) {
            bh[n] = *reinterpret_cast<const frag8*>(&Bs_hi[wc * 64 + n * 16 + fr][k0]);
            bl[n] = *reinterpret_cast<const frag8*>(&Bs_lo[wc * 64 + n * 16 + fr][k0]);
        }
        #pragma unroll
        for (int m = 0; m < 4; ++m) {
            #pragma unroll
            for (int n = 0; n < 4; ++n) {
                acc[m][n] = __builtin_amdgcn_mfma_f32_16x16x32_bf16(ah[m], bh[n], acc[m][n], 0, 0, 0);
                acc[m][n] = __builtin_amdgcn_mfma_f32_16x16x32_bf16(ah[m], bl[n], acc[m][n], 0, 0, 0);
                acc[m][n] = __builtin_amdgcn_mfma_f32_16x16x32_bf16(al[m], bh[n], acc[m][n], 0, 0, 0);
            }
        }
    }

    // epilogue: bias + SiLU, scalar stores (C frag: col=lane&15, row=(lane>>4)*4+j)
    #pragma unroll
    for (int n = 0; n < 4; ++n) {
        int col = col_base + wc * 64 + n * 16 + fr;
        float b = bias[col];
        #pragma unroll
        for (int m = 0; m < 4; ++m) {
            int rowb = row_base + wr * 64 + m * 16 + (lane >> 4) * 4;
            f32x4 v = acc[m][n];
            #pragma unroll
            for (int j = 0; j < 4; ++j) {
                int row = rowb + j;
                if (row < M) {
                    float x = v[j] + b;
                    out[(size_t)row * OUT_DIM + col] = x / (1.0f + expf(-x));
                }
            }
        }
    }
}

extern "C" void kernel_launch(void* const* d_in, const int* in_sizes, int n_in,
                              void* d_out, int out_size, void* d_ws, size_t ws_size,
                              hipStream_t stream)
{
    const float* feats  = (const float*)d_in[0];
    const float* W_conv = (const float*)d_in[1];
    const float* b_conv = (const float*)d_in[2];
    const float* W1     = (const float*)d_in[3];
    const float* b1     = (const float*)d_in[4];
    const float* W2     = (const float*)d_in[5];
    const float* b2     = (const float*)d_in[6];
    const int*   src    = (const int*)d_in[7];
    const int*   dst    = (const int*)d_in[8];
    float* out = (float*)d_out;

    // workspace layout (bytes):
    //   [0, 51,200,000)            h1 (50000x256 f32), aliases agg (dead by layer 2)
    //   [51,200,000, 51,400,000)   cnt_src (int)
    //   [51,400,000, 51,600,000)   cnt_dst (int)
    //   [51,600,000, 51,800,004)   offs (int[N+1])
    //   [51,800,016, 55,000,016)   edge_src (int[E])
    //   [55,001,600, 55,656,960)   pre-split transposed weights (bf16)
    char* ws = (char*)d_ws;
    float* h1       = (float*)(ws + 0);
    float* agg      = (float*)(ws + 0);
    int*   cnt_src  = (int*)(ws + 51200000);
    int*   cnt_dst  = (int*)(ws + 51400000);
    int*   offs     = (int*)(ws + 51600000);
    int*   edge_src = (int*)(ws + 51800016);
    ushort* Wtc_hi  = (ushort*)(ws + 55001600);              // 256x128
    ushort* Wtc_lo  = (ushort*)(ws + 55001600 + 65536);
    ushort* Wt1_hi  = (ushort*)(ws + 55001600 + 131072);     // 256x256
    ushort* Wt1_lo  = (ushort*)(ws + 55001600 + 262144);
    ushort* Wt2_hi  = (ushort*)(ws + 55001600 + 393216);
    ushort* Wt2_lo  = (ushort*)(ws + 55001600 + 524288);

    hipMemsetAsync(ws + 51200000, 0, 400000, stream);

    hist_kernel<<<(N_EDGES + 255) / 256, 256, 0, stream>>>(src, dst, cnt_src, cnt_dst, N_EDGES);
    scan_kernel<<<1, 1024, 0, stream>>>(cnt_dst, offs);
    build_csr_kernel<<<(N_EDGES + 255) / 256, 256, 0, stream>>>(src, dst, offs, cnt_dst, edge_src, N_EDGES);

    // weight pre-split (independent of graph work)
    wsplit_kernel<<<(IN_DIM * 256 + 255) / 256, 256, 0, stream>>>(W_conv, Wtc_hi, Wtc_lo, IN_DIM);
    wsplit_kernel<<<(OUT_DIM * 256 + 255) / 256, 256, 0, stream>>>(W1, Wt1_hi, Wt1_lo, OUT_DIM);
    wsplit_kernel<<<(OUT_DIM * 256 + 255) / 256, 256, 0, stream>>>(W2, Wt2_hi, Wt2_lo, OUT_DIM);

    {   // 32 lanes per node
        long long total = (long long)N_NODES * 32;
        int blocks = (int)((total + 255) / 256);
        aggregate_kernel<<<blocks, 256, 0, stream>>>(feats, edge_src, offs, cnt_src, agg, N_NODES);
    }

    dim3 ggrid(OUT_DIM / 128, (N_NODES + 127) / 128);   // (2, 391)
    // layer 1: d_out = silu(agg @ W_conv + b_conv)      (K=128)
    gemm_mfma_kernel<IN_DIM><<<ggrid, 256, 0, stream>>>(agg, Wtc_hi, Wtc_lo, b_conv, out, N_NODES);
    // layer 2: h1 = silu(d_out @ W1 + b1)               (K=256)
    gemm_mfma_kernel<OUT_DIM><<<ggrid, 256, 0, stream>>>(out, Wt1_hi, Wt1_lo, b1, h1, N_NODES);
    // layer 3: d_out = silu(h1 @ W2 + b2)               (K=256)
    gemm_mfma_kernel<OUT_DIM><<<ggrid, 256, 0, stream>>>(h1, Wt2_hi, Wt2_lo, b2, out, N_NODES);
}